// Round 10
// baseline (734.608 us; speedup 1.0000x reference)
//
#include <hip/hip_runtime.h>
#include <stdint.h>

// ---- problem constants ----
#define D_MODEL  2048
#define N_INTER  1408
#define SH_INTER 2816
#define T_TOK    2048
#define NSLOT    (T_TOK * 4)
#define MIB(x)   ((size_t)(x) << 20)

typedef __attribute__((ext_vector_type(8))) short bf16x8;
typedef __attribute__((ext_vector_type(4))) float f32x4;

__device__ __forceinline__ unsigned short f2bf(float f){
  unsigned int b = __builtin_bit_cast(unsigned int, f);
  b = (b + 0x7FFFu + ((b >> 16) & 1u)) >> 16;   // RNE, finite inputs
  return (unsigned short)b;
}
__device__ __forceinline__ float bf2f(unsigned short h){
  unsigned int b = ((unsigned int)h) << 16;
  return __builtin_bit_cast(float, b);
}

// async global->LDS, 16B per lane; LDS dest = wave-uniform base + lane*16,
// global source is PER-LANE (m173) -- used for the G/U straddle select below.
#define GLOAD16(gp, lp) __builtin_amdgcn_global_load_lds( \
    (const __attribute__((address_space(1))) unsigned int*)(gp), \
    (__attribute__((address_space(3))) unsigned int*)(lp), 16, 0, 0)

// ---------------- fp32 -> bf16 streaming convert ----------------
__global__ void cvt_bf16_kernel(const float* __restrict__ x,
                                unsigned short* __restrict__ o, int n4){
  const int stride = gridDim.x * blockDim.x;
  for (int i = blockIdx.x * blockDim.x + threadIdx.x; i < n4; i += stride){
    const float4 v = ((const float4*)x)[i];
    ushort4 u; u.x = f2bf(v.x); u.y = f2bf(v.y); u.z = f2bf(v.z); u.w = f2bf(v.w);
    ((ushort4*)o)[i] = u;
  }
}

// ---------------- phase A: convert x + all shared-expert weights ----------------
__global__ void cvt4_kernel(const float* __restrict__ x,  const float* __restrict__ Ws1,
                            const float* __restrict__ Ws3, const float* __restrict__ Ws2,
                            unsigned short* __restrict__ xbf, unsigned short* __restrict__ S1,
                            unsigned short* __restrict__ S3,  unsigned short* __restrict__ S2){
  const int N0 = T_TOK * D_MODEL / 4;
  const int NW = SH_INTER * D_MODEL / 4;
  const int total = N0 + 3 * NW;
  const int stride = gridDim.x * blockDim.x;
  for (int i = blockIdx.x * blockDim.x + threadIdx.x; i < total; i += stride){
    const float4* s; ushort4* d; int j;
    if (i < N0)            { s = (const float4*)x;   d = (ushort4*)xbf; j = i; }
    else if (i < N0 + NW)  { s = (const float4*)Ws1; d = (ushort4*)S1;  j = i - N0; }
    else if (i < N0 + 2*NW){ s = (const float4*)Ws3; d = (ushort4*)S3;  j = i - N0 - NW; }
    else                   { s = (const float4*)Ws2; d = (ushort4*)S2;  j = i - N0 - 2*NW; }
    const float4 v = s[j];
    ushort4 u; u.x = f2bf(v.x); u.y = f2bf(v.y); u.z = f2bf(v.z); u.w = f2bf(v.w);
    d[j] = u;
  }
}

// ---------------- gate: softmax + group-limited top-k ----------------
__global__ void gate_kernel(const float* __restrict__ x, const float* __restrict__ Wg,
                            int* __restrict__ cnt, int* __restrict__ list,
                            float* __restrict__ wslot){
  const int t = blockIdx.x;
  const int l = threadIdx.x;
  const int e = l & 15, q = l >> 4;
  const float* xr = x + (size_t)t * D_MODEL + q * 512;
  const float* wr = Wg + (size_t)e * D_MODEL + q * 512;
  float p = 0.f;
  #pragma unroll 4
  for (int i = 0; i < 512; i += 4){
    float4 xv = *(const float4*)(xr + i);
    float4 wv = *(const float4*)(wr + i);
    p += xv.x*wv.x + xv.y*wv.y + xv.z*wv.z + xv.w*wv.w;
  }
  p += __shfl_xor(p, 16);
  p += __shfl_xor(p, 32);
  float mx = p;
  for (int d = 1; d < 16; d <<= 1) mx = fmaxf(mx, __shfl_xor(mx, d));
  float ex = __expf(p - mx);
  float sum = ex;
  for (int d = 1; d < 16; d <<= 1) sum += __shfl_xor(sum, d);
  const float sc = ex / sum;
  float gm = fmaxf(sc, __shfl_xor(sc, 1));
  gm = fmaxf(gm, __shfl_xor(gm, 2));
  const float g0 = __shfl(gm, 0), g1 = __shfl(gm, 4),
              g2 = __shfl(gm, 8), g3 = __shfl(gm, 12);
  const int grp = e >> 2;
  const float gs[4] = {g0, g1, g2, g3};
  int grank = 0;
  #pragma unroll
  for (int j = 0; j < 4; ++j)
    if (gs[j] > gm || (gs[j] == gm && j < grp)) grank++;
  const float msc = (grank < 2) ? sc : -INFINITY;
  int erank = 0;
  #pragma unroll
  for (int j = 0; j < 16; ++j){
    const float oj = __shfl(msc, j);
    if (oj > msc || (oj == msc && j < e)) erank++;
  }
  if (q == 0 && erank < 4 && msc > -INFINITY){
    const int pos = atomicAdd(&cnt[e], 1);
    const int slot = (t << 2) | erank;
    list[e * T_TOK + pos] = slot;
    wslot[slot] = sc;            // ROUTE_SCALE = 1
  }
}

// ==== 8-wave 256x256x32 GEMM (512 threads, wave grid 2Mx4N, 128x64/wave) ====
// FLOP/staged-byte = 128 (2x the 128^2 tile) -> staging-delivery cap ~50% util.
// 3-deep LDS pipeline (96 KB, 1 block/CU), counted vmcnt(8/4/0) [R6-proven,
// 4 gloads/wave/tile], XOR-swizzled global_load_lds staging + XOR frag reads.
// MODE 0: linear A, B = G|U concat (straddle ok), bf16 out rows       [shared GU]
// MODE 1: linear A, single B, fp32 partial out at ks panel (KSPLIT)   [shared down]
// MODE 2: A gathered by token (list>>2), B = G|U concat, out at slot  [routed GU]
// MODE 3: A gathered by slot, single B, bf16 out at slot              [routed down]
// N = out width (=2*NI for GU modes); NI = G-panel width (straddle boundary).
template<int MODE, int KS>
__global__ __launch_bounds__(512, 2)
void gemm8_kernel(const unsigned short* __restrict__ A,
                  const unsigned short* __restrict__ BG,
                  const unsigned short* __restrict__ BU,
                  void* __restrict__ OutP,
                  const int* __restrict__ list,
                  const int* __restrict__ cnt,
                  int K, int N, int NI, int MT, int NT)
{
  constexpr bool GATHER = (MODE == 2 || MODE == 3);
  constexpr bool GU     = (MODE == 0 || MODE == 2);
  __shared__ unsigned short As[3 * 8192];   // 48 KB (3 x 256x32 bf16)
  __shared__ unsigned short Bs[3 * 8192];   // 48 KB

  // bijective XCD-chunked swizzle (all grids % 8 == 0)
  const int per = gridDim.x >> 3;
  const int gsw = (blockIdx.x & 7) * per + (blockIdx.x >> 3);
  const int mt = gsw % MT;
  const int rest = gsw / MT;
  const int nt = rest % NT;
  const int rest2 = rest / NT;
  const int ks = (KS > 1) ? (rest2 % KS) : 0;
  const int e  = GATHER ? rest2 : 0;
  const int cntE = GATHER ? cnt[e] : (MT * 256);
  if (mt * 256 >= cntE) return;

  const int tid = threadIdx.x, wid = tid >> 6, lane = tid & 63;
  const int sx   = ((lane & 3) ^ ((lane >> 3) & 3)) << 3;  // src 16B-slot XOR, shorts
  const int kOff = (KS > 1) ? ks * (K / KS) : 0;

  // ---- A staging: wave w covers rows [32w,32w+32), 2 insts x 16 rows ----
  const int rt0 = 32 * wid + (lane >> 2), rt1 = rt0 + 16;
  int ar0, ar1;
  if (GATHER){
    const int lim = cntE - 1;
    int p0 = mt * 256 + rt0; p0 = p0 < lim ? p0 : lim;
    int p1 = mt * 256 + rt1; p1 = p1 < lim ? p1 : lim;
    const int e0 = list[e * T_TOK + p0], e1 = list[e * T_TOK + p1];
    ar0 = (MODE == 2) ? (e0 >> 2) : e0;
    ar1 = (MODE == 2) ? (e1 >> 2) : e1;
  } else { ar0 = mt * 256 + rt0; ar1 = mt * 256 + rt1; }
  const unsigned short* pa0 = A + (size_t)ar0 * K + kOff + sx;
  const unsigned short* pa1 = A + (size_t)ar1 * K + kOff + sx;

  // ---- B staging (per-lane source; GU modes select G/U across the NI boundary) ----
  const unsigned short* pb0;
  const unsigned short* pb1;
  if (GU){
    const size_t eo = GATHER ? (size_t)e * NI * K : 0;
    const int g0 = nt * 256 + rt0, g1 = nt * 256 + rt1;
    pb0 = (g0 < NI ? BG + eo + (size_t)g0 * K : BU + eo + (size_t)(g0 - NI) * K) + sx;
    pb1 = (g1 < NI ? BG + eo + (size_t)g1 * K : BU + eo + (size_t)(g1 - NI) * K) + sx;
  } else {
    const unsigned short* base = BG + (GATHER ? (size_t)e * N * K : 0) + kOff;
    pb0 = base + (size_t)(nt * 256 + rt0) * K + sx;
    pb1 = base + (size_t)(nt * 256 + rt1) * K + sx;
  }

  const int w0 = (32 * wid) * 32, w1 = w0 + 512;   // shorts
  const int bufStr = 8192;

  // ---- fragment read offsets (XOR-swizzled) ----
  const int wm = wid >> 2, wn = wid & 3, lr = lane & 15, lq = lane >> 4;
  const int fx = (lq ^ ((lr >> 1) & 3)) << 3;
  int aoff[8], boff[4];
  #pragma unroll
  for (int m = 0; m < 8; ++m) aoff[m] = (wm * 128 + m * 16 + lr) * 32 + fx;
  #pragma unroll
  for (int n = 0; n < 4; ++n) boff[n] = (wn * 64 + n * 16 + lr) * 32 + fx;

  f32x4 acc[8][4];
  const f32x4 zero = {0.f, 0.f, 0.f, 0.f};
  #pragma unroll
  for (int m = 0; m < 8; ++m)
    #pragma unroll
    for (int n = 0; n < 4; ++n) acc[m][n] = zero;

  const int KT = (K / (KS > 1 ? KS : 1)) >> 5;
  // prologue: stage tiles 0,1,2
  #pragma unroll
  for (int t = 0; t < 3; ++t){
    GLOAD16(pa0, As + t * bufStr + w0);
    GLOAD16(pa1, As + t * bufStr + w1);
    GLOAD16(pb0, Bs + t * bufStr + w0);
    GLOAD16(pb1, Bs + t * bufStr + w1);
    pa0 += 32; pa1 += 32; pb0 += 32; pb1 += 32;
  }
  int c = 0;

  for (int kt = 0; kt < KT; ++kt){
    if (kt < KT - 2)       asm volatile("s_waitcnt vmcnt(8)" ::: "memory");
    else if (kt == KT - 2) asm volatile("s_waitcnt vmcnt(4)" ::: "memory");
    else                   asm volatile("s_waitcnt vmcnt(0)" ::: "memory");
    __builtin_amdgcn_s_barrier();            // tile kt visible to all waves

    const unsigned short* aC = As + c * bufStr;
    const unsigned short* bC = Bs + c * bufStr;
    bf16x8 af[8], bf[4];
    #pragma unroll
    for (int m = 0; m < 8; ++m) af[m] = *(const bf16x8*)(aC + aoff[m]);
    #pragma unroll
    for (int n = 0; n < 4; ++n) bf[n] = *(const bf16x8*)(bC + boff[n]);

    asm volatile("s_waitcnt lgkmcnt(0)" ::: "memory");
    __builtin_amdgcn_sched_barrier(0);       // rule #18
    __builtin_amdgcn_s_barrier();            // all waves done reading buf c

    if (kt + 3 < KT){                        // refill buf c with tile kt+3
      GLOAD16(pa0, As + c * bufStr + w0);
      GLOAD16(pa1, As + c * bufStr + w1);
      GLOAD16(pb0, Bs + c * bufStr + w0);
      GLOAD16(pb1, Bs + c * bufStr + w1);
      pa0 += 32; pa1 += 32; pb0 += 32; pb1 += 32;
    }

    __builtin_amdgcn_s_setprio(1);
    #pragma unroll
    for (int n = 0; n < 4; ++n)
      #pragma unroll
      for (int m = 0; m < 8; ++m)
        acc[m][n] = __builtin_amdgcn_mfma_f32_16x16x32_bf16(af[m], bf[n], acc[m][n], 0, 0, 0);
    __builtin_amdgcn_s_setprio(0);

    c = (c == 2) ? 0 : c + 1;
  }

  // ---- epilogue: C/D col = lane&15, row = (lane>>4)*4 + reg ----
  const int colBase = nt * 256 + wn * 64;
  #pragma unroll
  for (int m = 0; m < 8; ++m){
    #pragma unroll
    for (int r = 0; r < 4; ++r){
      const int grow = mt * 256 + wm * 128 + m * 16 + lq * 4 + r;
      if (MODE == 1){
        float* op = (float*)OutP + (size_t)ks * MT * 256 * N + (size_t)grow * N + colBase;
        #pragma unroll
        for (int n = 0; n < 4; ++n) op[n * 16 + lr] = acc[m][n][r];
      } else if (MODE == 0){
        unsigned short* op = (unsigned short*)OutP + (size_t)grow * N + colBase;
        #pragma unroll
        for (int n = 0; n < 4; ++n) op[n * 16 + lr] = f2bf(acc[m][n][r]);
      } else {
        if (grow >= cntE) continue;
        const int orow = list[e * T_TOK + grow];    // slot
        unsigned short* op = (unsigned short*)OutP + (size_t)orow * N + colBase;
        #pragma unroll
        for (int n = 0; n < 4; ++n) op[n * 16 + lr] = f2bf(acc[m][n][r]);
      }
    }
  }
}

// ---- SwiGLU on N-concat layout: H[r][i] = silu(GU[r][i]) * GU[r][NI+i] ----
__global__ void swiglu_split_kernel(const unsigned short* __restrict__ GU,
                                    unsigned short* __restrict__ H,
                                    int n8, int NI8){
  const int stride = gridDim.x * blockDim.x;
  for (int i = blockIdx.x * blockDim.x + threadIdx.x; i < n8; i += stride){
    const int r = i / NI8, ccol = i - r * NI8;
    const bf16x8 g = ((const bf16x8*)GU)[(size_t)r * 2 * NI8 + ccol];
    const bf16x8 u = ((const bf16x8*)GU)[(size_t)r * 2 * NI8 + NI8 + ccol];
    bf16x8 h;
    #pragma unroll
    for (int j = 0; j < 8; ++j){
      const float gv = bf2f((unsigned short)g[j]);
      const float uv = bf2f((unsigned short)u[j]);
      h[j] = (short)f2bf(gv / (1.f + __expf(-gv)) * uv);
    }
    ((bf16x8*)H)[i] = h;
  }
}

// ---- combine: out[t] = sum_{p<4} P[p][t] + sum_k wslot[4t+k] * H2[4t+k] ----
__global__ void combine_kernel(const unsigned short* __restrict__ H2,
                               const float* __restrict__ P,
                               const float* __restrict__ wslot,
                               float* __restrict__ out){
  const int t = blockIdx.x;
  const int ccol = threadIdx.x * 8;
  float w[4];
  #pragma unroll
  for (int k = 0; k < 4; ++k) w[k] = wslot[t * 4 + k];
  float a[8];
  #pragma unroll
  for (int j = 0; j < 8; ++j) a[j] = 0.f;
  #pragma unroll
  for (int p = 0; p < 4; ++p){
    const float* pp = P + (size_t)(p * T_TOK + t) * D_MODEL + ccol;
    #pragma unroll
    for (int j = 0; j < 8; ++j) a[j] += pp[j];
  }
  #pragma unroll
  for (int k = 0; k < 4; ++k){
    const bf16x8 hv = *(const bf16x8*)(H2 + (size_t)(t * 4 + k) * D_MODEL + ccol);
    #pragma unroll
    for (int j = 0; j < 8; ++j) a[j] += w[k] * bf2f((unsigned short)hv[j]);
  }
  float* o = out + (size_t)t * D_MODEL + ccol;
  #pragma unroll
  for (int j = 0; j < 8; ++j) o[j] = a[j];
}

extern "C" void kernel_launch(void* const* d_in, const int* in_sizes, int n_in,
                              void* d_out, int out_size, void* d_ws, size_t ws_size,
                              hipStream_t stream)
{
  const float* x   = (const float*)d_in[0];
  const float* Wg  = (const float*)d_in[1];
  const float* W1  = (const float*)d_in[2];
  const float* W3  = (const float*)d_in[3];
  const float* W2  = (const float*)d_in[4];
  const float* Ws1 = (const float*)d_in[5];
  const float* Ws3 = (const float*)d_in[6];
  const float* Ws2 = (const float*)d_in[7];
  float* out = (float*)d_out;

  // ---- workspace (~534 MiB used; harness poison shows ws ~700 MiB) ----
  char* ws = (char*)d_ws;
  int*   cnt   = (int*)(ws);                     // 64 B
  int*   list  = (int*)(ws + 4096);              // 128 KiB
  float* wslot = (float*)(ws + 4096 + 131072);   // 32 KiB
  unsigned short* xbf  = (unsigned short*)(ws + MIB(1));    // 8 MiB
  unsigned short* S1   = (unsigned short*)(ws + MIB(10));   // 11.5 MiB
  unsigned short* S3   = (unsigned short*)(ws + MIB(22));   // 11.5 MiB
  unsigned short* S2   = (unsigned short*)(ws + MIB(34));   // 11.5 MiB
  unsigned short* Hs   = (unsigned short*)(ws + MIB(46));   // 11.5 MiB
  unsigned short* GU_s = (unsigned short*)(ws + MIB(58));   // 23.1 MiB
  unsigned short* Hr   = (unsigned short*)(ws + MIB(82));   // 46.2 MiB (GU concat)
  unsigned short* Hc   = (unsigned short*)(ws + MIB(129));  // 23.1 MiB
  unsigned short* H2   = (unsigned short*)(ws + MIB(153));  // 33.6 MiB
  float*          P    = (float*)        (ws + MIB(187));   // 67.1 MiB (4 partials)
  unsigned short* W1b  = (unsigned short*)(ws + MIB(255));  // 92.3 MiB
  unsigned short* W3b  = (unsigned short*)(ws + MIB(348));  // 92.3 MiB
  unsigned short* W2b  = (unsigned short*)(ws + MIB(441));  // 92.3 MiB

  const int NW_R = 16 * N_INTER * D_MODEL / 4;

  hipMemsetAsync(cnt, 0, 4096, stream);
  cvt4_kernel<<<2048, 256, 0, stream>>>(x, Ws1, Ws3, Ws2, xbf, S1, S3, S2);
  gate_kernel<<<T_TOK, 64, 0, stream>>>(x, Wg, cnt, list, wslot);

  // shared GU (G|U concat): M=2048, N=5632, K=2048 -> GU_s ; grid 8x22=176
  gemm8_kernel<0, 1><<<176, 512, 0, stream>>>(xbf, S1, S3, GU_s, nullptr, nullptr,
                                              D_MODEL, 2 * SH_INTER, SH_INTER, 8, 22);
  cvt_bf16_kernel<<<4096, 256, 0, stream>>>(W1, W1b, NW_R);
  cvt_bf16_kernel<<<4096, 256, 0, stream>>>(W3, W3b, NW_R);
  swiglu_split_kernel<<<2048, 256, 0, stream>>>(GU_s, Hs, T_TOK * SH_INTER / 8, SH_INTER / 8);

  // shared down (K-split x4 -> fp32 partials): M=2048, N=2048, K=2816 ; grid 8x8x4=256
  gemm8_kernel<1, 4><<<256, 512, 0, stream>>>(Hs, S2, nullptr, P, nullptr, nullptr,
                                              SH_INTER, D_MODEL, 0, 8, 8);

  // routed GU (G|U concat, gathered): N=2816, K=2048 -> Hr[slot] ; grid 8x11x16=1408
  gemm8_kernel<2, 1><<<1408, 512, 0, stream>>>(xbf, W1b, W3b, Hr, list, cnt,
                                               D_MODEL, 2 * N_INTER, N_INTER, 8, 11);
  cvt_bf16_kernel<<<4096, 256, 0, stream>>>(W2, W2b, NW_R);
  swiglu_split_kernel<<<2048, 256, 0, stream>>>(Hr, Hc, NSLOT * N_INTER / 8, N_INTER / 8);

  // routed down (gathered by slot): N=2048, K=1408 -> H2[slot] ; grid 8x8x16=1024
  gemm8_kernel<3, 1><<<1024, 512, 0, stream>>>(Hc, W2b, nullptr, H2, list, cnt,
                                               N_INTER, D_MODEL, 0, 8, 8);

  combine_kernel<<<T_TOK, 256, 0, stream>>>(H2, P, wslot, out);
}

// Round 11
// 670.686 us; speedup vs baseline: 1.0953x; 1.0953x over previous
//
#include <hip/hip_runtime.h>
#include <stdint.h>

// ---- problem constants ----
#define D_MODEL  2048
#define N_INTER  1408
#define SH_INTER 2816
#define T_TOK    2048
#define NSLOT    (T_TOK * 4)
#define MIB(x)   ((size_t)(x) << 20)

typedef __attribute__((ext_vector_type(8))) short bf16x8;
typedef __attribute__((ext_vector_type(4))) float f32x4;

__device__ __forceinline__ unsigned short f2bf(float f){
  unsigned int b = __builtin_bit_cast(unsigned int, f);
  b = (b + 0x7FFFu + ((b >> 16) & 1u)) >> 16;   // RNE, finite inputs
  return (unsigned short)b;
}
__device__ __forceinline__ float bf2f(unsigned short h){
  unsigned int b = ((unsigned int)h) << 16;
  return __builtin_bit_cast(float, b);
}

// async global->LDS, 16B per lane; LDS dest = wave-uniform base + lane*16
#define GLOAD16(gp, lp) __builtin_amdgcn_global_load_lds( \
    (const __attribute__((address_space(1))) unsigned int*)(gp), \
    (__attribute__((address_space(3))) unsigned int*)(lp), 16, 0, 0)

// cvt tail executed by producer blocks inside GEMM launches
__device__ __forceinline__ void cvt_tail(const float* __restrict__ src,
                                         unsigned short* __restrict__ dst,
                                         int n4, int cb, int nblk, int tid){
  const float4* s = (const float4*)src;
  ushort4* d = (ushort4*)dst;
  const int stride = nblk * 256;
  for (int i = cb * 256 + tid; i < n4; i += stride){
    const float4 v = s[i];
    ushort4 u; u.x = f2bf(v.x); u.y = f2bf(v.y); u.z = f2bf(v.z); u.w = f2bf(v.w);
    d[i] = u;
  }
}

// ---------------- phase A: convert x + all shared-expert weights ----------------
// S1 and S3 are CONTIGUOUS (S3 = S1 + SH_INTER*D_MODEL) forming the G|U concat.
__global__ void cvt4_kernel(const float* __restrict__ x,  const float* __restrict__ Ws1,
                            const float* __restrict__ Ws3, const float* __restrict__ Ws2,
                            unsigned short* __restrict__ xbf, unsigned short* __restrict__ S1,
                            unsigned short* __restrict__ S3,  unsigned short* __restrict__ S2){
  const int N0 = T_TOK * D_MODEL / 4;
  const int NW = SH_INTER * D_MODEL / 4;
  const int total = N0 + 3 * NW;
  const int stride = gridDim.x * blockDim.x;
  for (int i = blockIdx.x * blockDim.x + threadIdx.x; i < total; i += stride){
    const float4* s; ushort4* d; int j;
    if (i < N0)            { s = (const float4*)x;   d = (ushort4*)xbf; j = i; }
    else if (i < N0 + NW)  { s = (const float4*)Ws1; d = (ushort4*)S1;  j = i - N0; }
    else if (i < N0 + 2*NW){ s = (const float4*)Ws3; d = (ushort4*)S3;  j = i - N0 - NW; }
    else                   { s = (const float4*)Ws2; d = (ushort4*)S2;  j = i - N0 - 2*NW; }
    const float4 v = s[j];
    ushort4 u; u.x = f2bf(v.x); u.y = f2bf(v.y); u.z = f2bf(v.z); u.w = f2bf(v.w);
    d[j] = u;
  }
}

// ---------------- gate: softmax + group-limited top-k ----------------
__global__ void gate_kernel(const float* __restrict__ x, const float* __restrict__ Wg,
                            int* __restrict__ cnt, int* __restrict__ list,
                            float* __restrict__ wslot){
  const int t = blockIdx.x;
  const int l = threadIdx.x;
  const int e = l & 15, q = l >> 4;
  const float* xr = x + (size_t)t * D_MODEL + q * 512;
  const float* wr = Wg + (size_t)e * D_MODEL + q * 512;
  float p = 0.f;
  #pragma unroll 4
  for (int i = 0; i < 512; i += 4){
    float4 xv = *(const float4*)(xr + i);
    float4 wv = *(const float4*)(wr + i);
    p += xv.x*wv.x + xv.y*wv.y + xv.z*wv.z + xv.w*wv.w;
  }
  p += __shfl_xor(p, 16);
  p += __shfl_xor(p, 32);
  float mx = p;
  for (int d = 1; d < 16; d <<= 1) mx = fmaxf(mx, __shfl_xor(mx, d));
  float ex = __expf(p - mx);
  float sum = ex;
  for (int d = 1; d < 16; d <<= 1) sum += __shfl_xor(sum, d);
  const float sc = ex / sum;
  float gm = fmaxf(sc, __shfl_xor(sc, 1));
  gm = fmaxf(gm, __shfl_xor(gm, 2));
  const float g0 = __shfl(gm, 0), g1 = __shfl(gm, 4),
              g2 = __shfl(gm, 8), g3 = __shfl(gm, 12);
  const int grp = e >> 2;
  const float gs[4] = {g0, g1, g2, g3};
  int grank = 0;
  #pragma unroll
  for (int j = 0; j < 4; ++j)
    if (gs[j] > gm || (gs[j] == gm && j < grp)) grank++;
  const float msc = (grank < 2) ? sc : -INFINITY;
  int erank = 0;
  #pragma unroll
  for (int j = 0; j < 16; ++j){
    const float oj = __shfl(msc, j);
    if (oj > msc || (oj == msc && j < e)) erank++;
  }
  if (q == 0 && erank < 4 && msc > -INFINITY){
    const int pos = atomicAdd(&cnt[e], 1);
    const int slot = (t << 2) | erank;
    list[e * T_TOK + pos] = slot;
    wslot[slot] = sc;            // ROUTE_SCALE = 1
  }
}

// ---- GEMM (R6-proven): BM=128 BN=128 BK=32, 4 waves, bf16 A and B ----
// 3-deep pipeline, counted s_waitcnt vmcnt(8/4/0); global_load_lds staging with
// pre-swizzled source + XOR read (0 bank conflicts, R4-verified).
// Blocks with bid >= gemmN are PRODUCER blocks: they stream-convert the next
// phase's weights fp32->bf16 on idle CU slots / HBM bandwidth, then exit.
// MODE 0: linear A, bf16 out     MODE 1: linear A, fp32 out
// MODE 2: gather A by token (entry>>2), bf16 out at slot
// MODE 3: gather A by slot (entry),     bf16 out at slot
template<int MODE>
__global__ __launch_bounds__(256, 3)
void gemm6_kernel(const unsigned short* __restrict__ A,
                  const unsigned short* __restrict__ B,
                  void* __restrict__ OutP,
                  const int* __restrict__ list,
                  const int* __restrict__ cnt,
                  int N, int K, int Astride, int MT, int NT,
                  const float* __restrict__ cvtSrc,
                  unsigned short* __restrict__ cvtDst,
                  int cvtN4, int gemmN)
{
  constexpr bool GATHER = (MODE >= 2);
  __shared__ unsigned short As[3 * 128 * 32];   // 24 KB
  __shared__ unsigned short Bs[3 * 128 * 32];   // 24 KB

  const int tid = threadIdx.x;
  const int bid = blockIdx.x;
  if (bid >= gemmN){                            // producer block
    cvt_tail(cvtSrc, cvtDst, cvtN4, bid - gemmN, gridDim.x - gemmN, tid);
    return;
  }

  // bijective XCD-chunked swizzle (gemmN % 8 == 0 in all launches)
  const int per = gemmN >> 3;
  const int gsw = (bid & 7) * per + (bid >> 3);
  const int mt   = gsw % MT;
  const int rest = gsw / MT;
  const int nt = GATHER ? (rest % NT) : rest;
  const int e  = GATHER ? (rest / NT) : 0;

  const int cntE = GATHER ? cnt[e] : (MT * 128);
  if (mt * 128 >= cntE) return;

  const int wid = tid >> 6, lane = tid & 63;

  // wave w stages tile rows [32w,32w+32) as 2 insts x 16 rows;
  // lane -> row += lane>>2, phys 16B-slot = lane&3, src slot = phys ^ ((row>>1)&3)
  const int rt0 = 32 * wid + (lane >> 2), rt1 = rt0 + 16;
  const int sxA = ((lane & 3) ^ ((lane >> 3) & 3)) << 3;   // shorts

  int ar0, ar1;
  if constexpr (GATHER){
    const int lim = cntE - 1;
    int p0 = mt * 128 + rt0; p0 = p0 < lim ? p0 : lim;
    int p1 = mt * 128 + rt1; p1 = p1 < lim ? p1 : lim;
    const int e0 = list[e * T_TOK + p0], e1 = list[e * T_TOK + p1];
    ar0 = (MODE == 2) ? (e0 >> 2) : e0;
    ar1 = (MODE == 2) ? (e1 >> 2) : e1;
  } else { ar0 = mt * 128 + rt0; ar1 = mt * 128 + rt1; }

  const unsigned short* pa0 = A + (size_t)ar0 * Astride + sxA;
  const unsigned short* pa1 = A + (size_t)ar1 * Astride + sxA;
  const unsigned short* pb0 = B + (GATHER ? (size_t)e * N * K : 0)
                            + (size_t)(nt * 128 + rt0) * K + sxA;
  const unsigned short* pb1 = pb0 + (size_t)16 * K;

  const int aW0 = (32 * wid) * 32, aW1 = aW0 + 16 * 32;    // shorts
  const int bufStride = 128 * 32;

  // fragment read offsets (XOR-swizzled, phys slot = lq ^ ((row>>1)&3))
  const int wr = wid >> 1, wc = wid & 1, lr = lane & 15, lq = lane >> 4;
  const int fx = ((lq ^ ((lr >> 1) & 3)) << 3);
  int aoff[4], boff[4];
  #pragma unroll
  for (int m = 0; m < 4; ++m) aoff[m] = (wr * 64 + m * 16 + lr) * 32 + fx;
  #pragma unroll
  for (int n = 0; n < 4; ++n) boff[n] = (wc * 64 + n * 16 + lr) * 32 + fx;

  f32x4 acc[4][4];
  const f32x4 zero = {0.f, 0.f, 0.f, 0.f};
  #pragma unroll
  for (int m = 0; m < 4; ++m)
    #pragma unroll
    for (int n = 0; n < 4; ++n) acc[m][n] = zero;

  const int KT = K >> 5;
  // prologue: stage tiles 0,1,2 into buffers 0,1,2
  #pragma unroll
  for (int t = 0; t < 3; ++t){
    GLOAD16(pa0, As + t * bufStride + aW0);
    GLOAD16(pa1, As + t * bufStride + aW1);
    GLOAD16(pb0, Bs + t * bufStride + aW0);
    GLOAD16(pb1, Bs + t * bufStride + aW1);
    pa0 += 32; pa1 += 32; pb0 += 32; pb1 += 32;
  }
  int c = 0;

  for (int kt = 0; kt < KT; ++kt){
    if (kt < KT - 2)       asm volatile("s_waitcnt vmcnt(8)" ::: "memory");
    else if (kt == KT - 2) asm volatile("s_waitcnt vmcnt(4)" ::: "memory");
    else                   asm volatile("s_waitcnt vmcnt(0)" ::: "memory");
    __builtin_amdgcn_s_barrier();            // tile kt visible to all waves

    const unsigned short* aC = As + c * bufStride;
    const unsigned short* bC = Bs + c * bufStride;
    bf16x8 af[4], bf[4];
    #pragma unroll
    for (int m = 0; m < 4; ++m) af[m] = *(const bf16x8*)(aC + aoff[m]);
    #pragma unroll
    for (int n = 0; n < 4; ++n) bf[n] = *(const bf16x8*)(bC + boff[n]);

    asm volatile("s_waitcnt lgkmcnt(0)" ::: "memory");  // my reads complete
    __builtin_amdgcn_sched_barrier(0);                  // rule #18
    __builtin_amdgcn_s_barrier();            // all waves done reading buf c

    if (kt + 3 < KT){                        // refill buf c with tile kt+3
      GLOAD16(pa0, As + c * bufStride + aW0);
      GLOAD16(pa1, As + c * bufStride + aW1);
      GLOAD16(pb0, Bs + c * bufStride + aW0);
      GLOAD16(pb1, Bs + c * bufStride + aW1);
      pa0 += 32; pa1 += 32; pb0 += 32; pb1 += 32;
    }

    #pragma unroll
    for (int n = 0; n < 4; ++n)
      #pragma unroll
      for (int m = 0; m < 4; ++m)
        acc[m][n] = __builtin_amdgcn_mfma_f32_16x16x32_bf16(af[m], bf[n], acc[m][n], 0, 0, 0);

    c = (c == 2) ? 0 : c + 1;
  }

  // ---- epilogue: C/D col = lane&15, row = (lane>>4)*4 + reg ----
  const int colBase = nt * 128 + wc * 64;
  #pragma unroll
  for (int m = 0; m < 4; ++m){
    #pragma unroll
    for (int r = 0; r < 4; ++r){
      const int grow = mt * 128 + wr * 64 + m * 16 + lq * 4 + r;
      if constexpr (MODE == 1){
        float* op = (float*)OutP + (size_t)grow * N + colBase;
        #pragma unroll
        for (int n = 0; n < 4; ++n) op[n * 16 + lr] = acc[m][n][r];
      } else if constexpr (MODE == 0){
        unsigned short* op = (unsigned short*)OutP + (size_t)grow * N + colBase;
        #pragma unroll
        for (int n = 0; n < 4; ++n) op[n * 16 + lr] = f2bf(acc[m][n][r]);
      } else {
        if (grow >= cntE) continue;
        const int orow = list[e * T_TOK + grow];    // slot
        unsigned short* op = (unsigned short*)OutP + (size_t)orow * N + colBase;
        #pragma unroll
        for (int n = 0; n < 4; ++n) op[n * 16 + lr] = f2bf(acc[m][n][r]);
      }
    }
  }
}

// ---- SwiGLU in place on N-concat rows: GU[r][c] = silu(GU[r][c])*GU[r][NI+c] ----
__global__ void swiglu_ip_kernel(unsigned short* __restrict__ GU, int n8, int NI8){
  const int stride = gridDim.x * blockDim.x;
  bf16x8* p = (bf16x8*)GU;
  for (int i = blockIdx.x * blockDim.x + threadIdx.x; i < n8; i += stride){
    const int r = i / NI8, ccol = i - r * NI8;
    const size_t gi = (size_t)r * 2 * NI8 + ccol;
    const bf16x8 g = p[gi];
    const bf16x8 u = p[gi + NI8];
    bf16x8 h;
    #pragma unroll
    for (int j = 0; j < 8; ++j){
      const float gv = bf2f((unsigned short)g[j]);
      const float uv = bf2f((unsigned short)u[j]);
      h[j] = (short)f2bf(gv / (1.f + __expf(-gv)) * uv);
    }
    p[gi] = h;
  }
}

// ---- SwiGLU, separate buffers, in place into G ----
__global__ void swiglu2_kernel(unsigned short* __restrict__ G,
                               const unsigned short* __restrict__ U, int n8){
  const int stride = gridDim.x * blockDim.x;
  for (int i = blockIdx.x * blockDim.x + threadIdx.x; i < n8; i += stride){
    const bf16x8 g = ((const bf16x8*)G)[i];
    const bf16x8 u = ((const bf16x8*)U)[i];
    bf16x8 h;
    #pragma unroll
    for (int j = 0; j < 8; ++j){
      const float gv = bf2f((unsigned short)g[j]);
      const float uv = bf2f((unsigned short)u[j]);
      h[j] = (short)f2bf(gv / (1.f + __expf(-gv)) * uv);
    }
    ((bf16x8*)G)[i] = h;
  }
}

// ---- combine: out[t] += sum_k wslot[4t+k] * H2[4t+k] ----
__global__ void combine_kernel(const unsigned short* __restrict__ H2,
                               const float* __restrict__ wslot,
                               float* __restrict__ out){
  const int t = blockIdx.x;
  const int ccol = threadIdx.x * 8;
  float w[4];
  #pragma unroll
  for (int k = 0; k < 4; ++k) w[k] = wslot[t * 4 + k];
  float* o = out + (size_t)t * D_MODEL + ccol;
  float a[8];
  #pragma unroll
  for (int j = 0; j < 8; ++j) a[j] = o[j];
  #pragma unroll
  for (int k = 0; k < 4; ++k){
    const bf16x8 hv = *(const bf16x8*)(H2 + (size_t)(t * 4 + k) * D_MODEL + ccol);
    #pragma unroll
    for (int j = 0; j < 8; ++j) a[j] += w[k] * bf2f((unsigned short)hv[j]);
  }
  #pragma unroll
  for (int j = 0; j < 8; ++j) o[j] = a[j];
}

extern "C" void kernel_launch(void* const* d_in, const int* in_sizes, int n_in,
                              void* d_out, int out_size, void* d_ws, size_t ws_size,
                              hipStream_t stream)
{
  const float* x   = (const float*)d_in[0];
  const float* Wg  = (const float*)d_in[1];
  const float* W1  = (const float*)d_in[2];
  const float* W3  = (const float*)d_in[3];
  const float* W2  = (const float*)d_in[4];
  const float* Ws1 = (const float*)d_in[5];
  const float* Ws3 = (const float*)d_in[6];
  const float* Ws2 = (const float*)d_in[7];
  float* out = (float*)d_out;

  // ---- workspace (~430 MiB used; harness poison shows ws ~700 MiB) ----
  char* ws = (char*)d_ws;
  int*   cnt   = (int*)(ws);                     // 64 B
  int*   list  = (int*)(ws + 4096);              // 128 KiB
  float* wslot = (float*)(ws + 4096 + 131072);   // 32 KiB
  unsigned short* xbf  = (unsigned short*)(ws + MIB(1));    // 8 MiB
  unsigned short* S1   = (unsigned short*)(ws + MIB(10));   // 23 MiB: Ws1 || Ws3 concat
  unsigned short* S3   = S1 + (size_t)SH_INTER * D_MODEL;
  unsigned short* S2   = (unsigned short*)(ws + MIB(34));   // 11.5 MiB
  unsigned short* GU_s = (unsigned short*)(ws + MIB(46));   // 23.1 MiB (shared G|U)
  unsigned short* Gbuf = (unsigned short*)(ws + MIB(70));   // 23.1 MiB (routed G -> H)
  unsigned short* Ubuf = (unsigned short*)(ws + MIB(94));   // 23.1 MiB (routed U)
  unsigned short* H2   = (unsigned short*)(ws + MIB(118));  // 33.6 MiB
  unsigned short* W1b  = (unsigned short*)(ws + MIB(152));  // 92.3 MiB
  unsigned short* W3b  = (unsigned short*)(ws + MIB(245));  // 92.3 MiB
  unsigned short* W2b  = (unsigned short*)(ws + MIB(338));  // 92.3 MiB

  const int NW_R = 16 * N_INTER * D_MODEL / 4;   // float4 count per routed weight set

  hipMemsetAsync(cnt, 0, 4096, stream);
  // phase A: x + shared weights -> bf16
  cvt4_kernel<<<2048, 256, 0, stream>>>(x, Ws1, Ws3, Ws2, xbf, S1, S3, S2);
  gate_kernel<<<T_TOK, 64, 0, stream>>>(x, Wg, cnt, list, wslot);

  // shared G+U concat (N=5632): grid 704 active + 1344 producers (W1 -> W1b)
  gemm6_kernel<0><<<704 + 1344, 256, 0, stream>>>(
      xbf, S1, GU_s, nullptr, nullptr, 2 * SH_INTER, D_MODEL, D_MODEL, 16, 44,
      W1, W1b, NW_R, 704);
  swiglu_ip_kernel<<<2048, 256, 0, stream>>>(GU_s, T_TOK * SH_INTER / 8, SH_INTER / 8);

  // shared down (strided A over concat G-half) -> out ; producers W3 -> W3b
  gemm6_kernel<1><<<256 + 1792, 256, 0, stream>>>(
      GU_s, S2, out, nullptr, nullptr, D_MODEL, SH_INTER, 2 * SH_INTER, 16, 16,
      W3, W3b, NW_R, 256);

  // routed G (gathered by token) -> Gbuf[slot] ; producers W2 -> W2b
  // active GEMM blocks ~704 <= 768 resident slots -> producers co-resident
  gemm6_kernel<2><<<2816 + 1280, 256, 0, stream>>>(
      xbf, W1b, Gbuf, list, cnt, N_INTER, D_MODEL, D_MODEL, 16, 11,
      W2, W2b, NW_R, 2816);

  // routed U -> Ubuf[slot] (no tail)
  gemm6_kernel<2><<<2816, 256, 0, stream>>>(
      xbf, W3b, Ubuf, list, cnt, N_INTER, D_MODEL, D_MODEL, 16, 11,
      nullptr, nullptr, 0, 2816);

  swiglu2_kernel<<<2048, 256, 0, stream>>>(Gbuf, Ubuf, NSLOT * N_INTER / 8);

  // routed down (gathered by slot) -> H2[slot]
  gemm6_kernel<3><<<4096, 256, 0, stream>>>(
      Gbuf, W2b, H2, list, cnt, D_MODEL, N_INTER, N_INTER, 16, 16,
      nullptr, nullptr, 0, 4096);

  combine_kernel<<<T_TOK, 256, 0, stream>>>(H2, wslot, out);
}